// Round 8
// baseline (635.263 us; speedup 1.0000x reference)
//
#include <hip/hip_runtime.h>

#define NYTOT 16384
#define NXP 4096
#define MTOT 65536   // B * NY
#define CYC 128
#define CXC 256
#define DIMC 384

typedef __attribute__((ext_vector_type(8))) _Float16 half8;
typedef __attribute__((ext_vector_type(4))) _Float16 half4;
typedef __attribute__((ext_vector_type(4))) float floatx4;

using half_t = _Float16;

struct alignas(16) HF8 { half_t h[8]; };

__device__ __forceinline__ float fmed3(float a, float b, float c) {
  return __builtin_amdgcn_fmed3f(a, b, c);
}

// ---------------- K0a: build xq[b][j] = {x0,x1,x2,sx} (ref-order sx) ------
__global__ __launch_bounds__(1024) void xq_prep(
    const float* __restrict__ x_points, float4* __restrict__ xq) {
#pragma clang fp contract(off)
  int j = blockIdx.x * 1024 + threadIdx.x;          // 0..16383
  int b = j >> 12, jj = j & 4095;
  const float* p = x_points + (size_t)b * NXP * 3 + 3 * jj;
  float x0 = p[0], x1 = p[1], x2 = p[2];
  float sx = (x0 * x0 + x1 * x1) + x2 * x2;         // ref order
  float4 v; v.x = x0; v.y = x1; v.z = x2; v.w = sx;
  xq[j] = v;
}

// ---------------- K0b: convert W1/W2/W3 fp32 -> fp16 tables ----------------
__global__ __launch_bounds__(256) void wconv_kernel(
    const float* __restrict__ W1, const float* __restrict__ W2,
    const float* __restrict__ W3, half_t* __restrict__ o1,
    half_t* __restrict__ o2, half_t* __restrict__ o3) {
  int i = blockIdx.x * 256 + threadIdx.x;
  if (i < 196608) o1[i] = (half_t)W1[i];
  else if (i < 327680) o2[i - 196608] = (half_t)W2[i - 196608];
  else if (i < 360448) o3[i - 327680] = (half_t)W3[i - 327680];
}

// ---------------- K1: 3-NN interpolation + concat -> A0 fp16 [M, 384] ----
// Distances mirror numpy BIT-EXACTLY: fp32, contract(off), left-assoc,
// d = (sy + sx) - 2*inner. 1 y per lane, 8 j-segments (one per wave),
// wave-uniform candidate loads. Two-phase: value-only med3 top-3 -> global
// t2 per y -> gated stable index recovery. Merges iterate segments in
// ascending-j order => lowest-index-wins ties preserved.
// Grid 1024 x 512thr: 4 blocks/CU -> 32 waves/CU (full occupancy).
__global__ __launch_bounds__(512, 4) void interp_kernel(
    const float* __restrict__ y_points, const float* __restrict__ y_feats,
    const float* __restrict__ x_feats, const float4* __restrict__ xq,
    half_t* __restrict__ A0) {
#pragma clang fp contract(off)
  __shared__ float pd[8][64][3];          // 6 KB partial dists
  __shared__ int   pi[8][64][3];          // 6 KB partial idx
  __shared__ float t2s[64];
  __shared__ float sw[3][64];
  __shared__ int   si[3][64];
  const int base = blockIdx.x * 64;       // first global y-row of this block
  const int b = base >> 14;
  const int t = threadIdx.x;
  const int lane = t & 63;
  const int seg = t >> 6;                 // 0..7

  const int m = base + lane;              // global y row
  const float* yp = y_points + (size_t)m * 3;
  float y0 = yp[0], y1 = yp[1], y2 = yp[2];
  float sy = (y0 * y0 + y1 * y1) + y2 * y2;

  const float4* xqs = xq + (size_t)b * NXP;
  const int jb = seg * 512;

  // ---- phase 1: value-only top-3 via med3/min ----
  float d0 = 1e30f, d1 = 1e30f, d2 = 1e30f;
#pragma unroll 8
  for (int jj = 0; jj < 512; ++jj) {
    float4 p = xqs[jb + jj];                        // wave-uniform load
    float inner = (y0 * p.x + y1 * p.y) + y2 * p.z; // ref einsum order, no FMA
    float d = (sy + p.w) - 2.0f * inner;            // ref expression tree
    d2 = fmed3(d, d1, d2);
    d1 = fmed3(d, d0, d1);
    d0 = fminf(d, d0);
  }
  pd[seg][lane][0] = d0; pd[seg][lane][1] = d1; pd[seg][lane][2] = d2;
  __syncthreads();

  // global 3rd-smallest per y
  if (t < 64) {
    float m0 = 1e30f, m1 = 1e30f, m2 = 1e30f;
#pragma unroll
    for (int s = 0; s < 8; ++s)
#pragma unroll
      for (int c = 0; c < 3; ++c) {
        float v = pd[s][t][c];
        m2 = fmed3(v, m1, m2);
        m1 = fmed3(v, m0, m1);
        m0 = fminf(v, m0);
      }
    t2s[t] = m2;
  }
  __syncthreads();

  // ---- phase 2: gated stable index recovery ----
  const float t2 = t2s[lane];
  float e0 = 1e30f, e1 = 1e30f, e2 = 1e30f;
  int k0 = 0, k1 = 0, k2 = 0;
#pragma unroll 4
  for (int jj = 0; jj < 512; ++jj) {
    float4 p = xqs[jb + jj];
    float inner = (y0 * p.x + y1 * p.y) + y2 * p.z;
    float d = (sy + p.w) - 2.0f * inner;
    if (d <= t2) {                        // rare: wave skips via execz
      bool l0 = d < e0, l1 = d < e1, l2 = d < e2;   // strict <: stable
      e2 = l1 ? e1 : (l2 ? d : e2);  k2 = l1 ? k1 : (l2 ? (jb + jj) : k2);
      e1 = l0 ? e0 : (l1 ? d : e1);  k1 = l0 ? k0 : (l1 ? (jb + jj) : k1);
      e0 = l0 ? d : e0;              k0 = l0 ? (jb + jj) : k0;
    }
  }
  pd[seg][lane][0] = e0; pd[seg][lane][1] = e1; pd[seg][lane][2] = e2;
  pi[seg][lane][0] = k0; pi[seg][lane][1] = k1; pi[seg][lane][2] = k2;
  __syncthreads();

  // 24-way stable merge (seg-ascending) + weights
  if (t < 64) {
    float f0 = 1e30f, f1 = 1e30f, f2 = 1e30f;
    int m0i = 0, m1i = 0, m2i = 0;
#pragma unroll
    for (int s = 0; s < 8; ++s)
#pragma unroll
      for (int c = 0; c < 3; ++c) {
        float d = pd[s][t][c]; int j = pi[s][t][c];
        bool l0 = d < f0, l1 = d < f1, l2 = d < f2;
        f2 = l1 ? f1 : (l2 ? d : f2);  m2i = l1 ? m1i : (l2 ? j : m2i);
        f1 = l0 ? f0 : (l1 ? d : f1);  m1i = l0 ? m0i : (l1 ? j : m1i);
        f0 = l0 ? d : f0;              m0i = l0 ? j : m0i;
      }
    float w0 = 1.0f / (f0 + 1e-8f), w1 = 1.0f / (f1 + 1e-8f), w2 = 1.0f / (f2 + 1e-8f);
    float ws = (w0 + w1) + w2;
    sw[0][t] = w0 / ws; sw[1][t] = w1 / ws; sw[2][t] = w2 / ws;
    si[0][t] = m0i; si[1][t] = m1i; si[2][t] = m2i;
  }
  __syncthreads();

  // ---- gather: vectorized float4 rows; weighted sum is continuous math
  const floatx4* xf4 = (const floatx4*)(x_feats + (size_t)b * NXP * CXC);
  const floatx4* yf4 = (const floatx4*)(y_feats + (size_t)base * CYC);
  half_t* fb = A0 + (size_t)base * DIMC;
  {
    const int q = t & 63;           // float4 index within 256-ch row
    const int ys = t >> 6;          // 8 y-groups
    for (int y2 = ys; y2 < 64; y2 += 8) {
      int j0 = si[0][y2], j1 = si[1][y2], j2 = si[2][y2];
      float a0 = sw[0][y2], a1 = sw[1][y2], a2 = sw[2][y2];
      floatx4 v0 = xf4[(size_t)j0 * 64 + q];
      floatx4 v1 = xf4[(size_t)j1 * 64 + q];
      floatx4 v2 = xf4[(size_t)j2 * 64 + q];
      half4 h;
#pragma unroll
      for (int e = 0; e < 4; ++e)
        h[e] = (half_t)fmaf(v2[e], a2, fmaf(v1[e], a1, v0[e] * a0));
      *(half4*)&fb[(size_t)y2 * DIMC + CYC + q * 4] = h;
    }
  }
  {
    const int q2 = t & 31;          // float4 index within 128-ch row
    const int ys2 = t >> 5;         // 16 y-groups
    for (int y2 = ys2; y2 < 64; y2 += 16) {
      floatx4 v = yf4[(size_t)y2 * 32 + q2];
      half4 h;
#pragma unroll
      for (int e = 0; e < 4; ++e) h[e] = (half_t)v[e];
      *(half4*)&fb[(size_t)y2 * DIMC + q2 * 4] = h;
    }
  }
}

// ---------------- GEMM: C[M,O] = A[M,K](fp16) * Wh[O,K](fp16)^T + bias ---
// 128x128 tile, BK=64, 4 waves (2x2), mfma_f32_16x16x32_f16.
// BOTH operands staged via global_load_lds width-16 (m97 pattern).
// Fused BN stats: per-channel sum/sumsq of z reduced in-wave, atomicAdd.
template<int K, int O>
__global__ __launch_bounds__(256) void gemm_f16(
    const half_t* __restrict__ A, const half_t* __restrict__ Wh,
    const float* __restrict__ bias, half_t* __restrict__ C,
    float* __restrict__ sums) {
  __shared__ __align__(16) short As[8][2][512];   // [m_sub][k_sub][lane*8+e]
  __shared__ __align__(16) short Bs[8][2][512];
  const int m0 = blockIdx.x * 128;
  const int n0 = blockIdx.y * 128;
  const int tid = threadIdx.x;
  const int lane = tid & 63;
  const int wid = tid >> 6;
  const int wm = wid >> 1, wn = wid & 1;
  const int lm = lane & 15;            // row within 16-subtile
  const int lk = (lane >> 4) * 8;      // k offset within 32
  floatx4 acc[4][4] = {};

  for (int k0 = 0; k0 < K; k0 += 64) {
    __syncthreads();
#pragma unroll
    for (int c = 0; c < 8; ++c) {
      int id = wid * 8 + c;            // 0..15 -> A chunks, 16..31 -> B chunks
      int sub = (id & 15) >> 1;
      int ks = id & 1;
      const half_t* src;
      short* dst;
      if (id < 16) {
        src = A + (size_t)(m0 + sub * 16 + lm) * K + (k0 + ks * 32 + lk);
        dst = &As[sub][ks][0];
      } else {
        src = Wh + (size_t)(n0 + sub * 16 + lm) * K + (k0 + ks * 32 + lk);
        dst = &Bs[sub][ks][0];
      }
      __builtin_amdgcn_global_load_lds(
          (const __attribute__((address_space(1))) void*)src,
          (__attribute__((address_space(3))) void*)dst, 16, 0, 0);
    }
    __syncthreads();
#pragma unroll
    for (int ks = 0; ks < 2; ++ks) {
      half8 af[4], bfm[4];
#pragma unroll
      for (int i = 0; i < 4; ++i) af[i] = *(const half8*)&As[wm * 4 + i][ks][lane * 8];
#pragma unroll
      for (int j = 0; j < 4; ++j) bfm[j] = *(const half8*)&Bs[wn * 4 + j][ks][lane * 8];
#pragma unroll
      for (int i = 0; i < 4; ++i)
#pragma unroll
        for (int j = 0; j < 4; ++j)
          acc[i][j] = __builtin_amdgcn_mfma_f32_16x16x32_f16(af[i], bfm[j], acc[i][j], 0, 0, 0);
    }
  }

  // epilogue: C/D layout col=lane&15, row=(lane>>4)*4+r; fused BN stats
#pragma unroll
  for (int j = 0; j < 4; ++j) {
    int nn = n0 + wn * 64 + j * 16 + lm;
    float bv = bias[nn];
    float psum = 0.f, psq = 0.f;
#pragma unroll
    for (int i = 0; i < 4; ++i) {
      int mr = m0 + wm * 64 + i * 16 + (lane >> 4) * 4;
#pragma unroll
      for (int rr = 0; rr < 4; ++rr) {
        float z = acc[i][j][rr] + bv;
        C[(size_t)(mr + rr) * O + nn] = (half_t)z;
        psum += z; psq += z * z;
      }
    }
    psum += __shfl_xor(psum, 16, 64); psq += __shfl_xor(psq, 16, 64);
    psum += __shfl_xor(psum, 32, 64); psq += __shfl_xor(psq, 32, 64);
    if ((lane >> 4) == 0) {
      atomicAdd(&sums[nn], psum);
      atomicAdd(&sums[O + nn], psq);
    }
  }
}

// -------- in-place BN + ReLU, finalize inlined per block (O pow2) --------
__global__ __launch_bounds__(256) void bnrelu_kernel(
    half_t* __restrict__ Z, const float* __restrict__ sums,
    const float* __restrict__ g, const float* __restrict__ be, int O) {
  __shared__ float ssl[1024];
  for (int c = threadIdx.x; c < O; c += 256) {
    const float invN = 1.0f / 65536.0f;
    float mean = sums[c] * invN;
    float var = sums[O + c] * invN - mean * mean;
    float sc = g[c] / sqrtf(var + 1e-5f);
    float sh = be[c] - mean * sc;
    if (!isfinite(sc) || !isfinite(sh)) { sc = 1.0f; sh = 0.0f; }
    ssl[c] = sc; ssl[O + c] = sh;
  }
  __syncthreads();
  size_t i = (size_t)blockIdx.x * 256 + threadIdx.x;
  int c0 = (int)((i * 8) & (size_t)(O - 1));
  HF8 v = ((const HF8*)Z)[i];
#pragma unroll
  for (int e = 0; e < 8; ++e) {
    int cc = c0 + e;
    float f = fmaxf((float)v.h[e] * ssl[cc] + ssl[O + cc], 0.f);
    v.h[e] = (half_t)f;
  }
  ((HF8*)Z)[i] = v;
}

// ---- layer3 BN + ReLU + transpose to [B, C, N] fp32, finalize inlined ----
__global__ __launch_bounds__(256) void bn_transpose_kernel(
    const half_t* __restrict__ Z3, const float* __restrict__ sums,
    const float* __restrict__ g, const float* __restrict__ be,
    float* __restrict__ out) {
  __shared__ float tile[64][129];
  __shared__ float ssl[256];
  const int t = threadIdx.x;
  if (t < 128) {
    const float invN = 1.0f / 65536.0f;
    float mean = sums[t] * invN;
    float var = sums[128 + t] * invN - mean * mean;
    float sc = g[t] / sqrtf(var + 1e-5f);
    float sh = be[t] - mean * sc;
    if (!isfinite(sc) || !isfinite(sh)) { sc = 1.0f; sh = 0.0f; }
    ssl[t] = sc; ssl[128 + t] = sh;
  }
  __syncthreads();
  const int r0 = blockIdx.x * 64;
  const int b = r0 >> 14;
  const int n0 = r0 & (NYTOT - 1);
  const int cl = t & 127, rl = t >> 7;      // 2 rows per pass
  for (int p = 0; p < 32; ++p) {
    int rr = p * 2 + rl;
    float v = (float)Z3[(size_t)(r0 + rr) * 128 + cl];
    tile[rr][cl] = fmaxf(v * ssl[cl] + ssl[128 + cl], 0.f);
  }
  __syncthreads();
  const int nl = t & 63, cj = t >> 6;       // 4 channels per pass
  for (int p = 0; p < 32; ++p) {
    int c = p * 4 + cj;
    out[(size_t)b * 128 * NYTOT + (size_t)c * NYTOT + n0 + nl] = tile[nl][c];
  }
}

extern "C" void kernel_launch(void* const* d_in, const int* in_sizes, int n_in,
                              void* d_out, int out_size, void* d_ws, size_t ws_size,
                              hipStream_t stream) {
  const float* y_points = (const float*)d_in[0];
  const float* y_feats  = (const float*)d_in[1];
  const float* x_points = (const float*)d_in[2];
  const float* x_feats  = (const float*)d_in[3];
  const float* W1 = (const float*)d_in[4];  const float* b1 = (const float*)d_in[5];
  const float* g1 = (const float*)d_in[6];  const float* be1 = (const float*)d_in[7];
  const float* W2 = (const float*)d_in[8];  const float* b2 = (const float*)d_in[9];
  const float* g2 = (const float*)d_in[10]; const float* be2 = (const float*)d_in[11];
  const float* W3 = (const float*)d_in[12]; const float* b3 = (const float*)d_in[13];
  const float* g3 = (const float*)d_in[14]; const float* be3 = (const float*)d_in[15];

  // workspace layout (peak 117,447,680 B — proven to fit):
  //   [0, 50.33MB)        : A0 fp16 [M,384]  (later aliased by z2)
  //   [50.33MB, 117.44MB) : z1 fp16 [M,512]  (later aliased by z3)
  //   [117.44MB, +7KB)    : BN sums
  // d_out (33.5 MB) doubles as scratch until the final transpose:
  //   xq @0 (256KB), Wh1 @262144 (384KB), Wh2 @655360 (256KB), Wh3 @917504 (64KB)
  char* ws = (char*)d_ws;
  half_t* A0 = (half_t*)ws;                      // 65536*384*2 = 50,331,648
  half_t* z1 = (half_t*)(ws + 50331648);         // 65536*512*2 = 67,108,864
  half_t* z2 = (half_t*)ws;                      // alias A0 (dead after gemm1)
  half_t* z3 = (half_t*)(ws + 50331648);         // alias z1 (dead after gemm2)
  float* st = (float*)(ws + 117440512);
  char* sc = (char*)d_out;
  float4* xq  = (float4*)sc;
  half_t* Wh1 = (half_t*)(sc + 262144);
  half_t* Wh2 = (half_t*)(sc + 655360);
  half_t* Wh3 = (half_t*)(sc + 917504);
  // st floats: sum1/sq1 @0 (1024), sum2/sq2 @1024 (512), sum3/sq3 @1536 (256)
  hipMemsetAsync(st, 0, 1792 * sizeof(float), stream);

  xq_prep<<<16, 1024, 0, stream>>>(x_points, xq);
  wconv_kernel<<<1408, 256, 0, stream>>>(W1, W2, W3, Wh1, Wh2, Wh3);
  interp_kernel<<<1024, 512, 0, stream>>>(y_points, y_feats, x_feats, xq, A0);

  gemm_f16<384, 512><<<dim3(512, 4), 256, 0, stream>>>(A0, Wh1, b1, z1, st + 0);
  bnrelu_kernel<<<16384, 256, 0, stream>>>(z1, st + 0, g1, be1, 512);

  gemm_f16<512, 256><<<dim3(512, 2), 256, 0, stream>>>(z1, Wh2, b2, z2, st + 1024);
  bnrelu_kernel<<<8192, 256, 0, stream>>>(z2, st + 1024, g2, be2, 256);

  gemm_f16<256, 128><<<dim3(512, 1), 256, 0, stream>>>(z2, Wh3, b3, z3, st + 1536);

  bn_transpose_kernel<<<1024, 256, 0, stream>>>(z3, st + 1536, g3, be3, (float*)d_out);
}